// Round 1
// baseline (261.810 us; speedup 1.0000x reference)
//
#include <hip/hip_runtime.h>

typedef __attribute__((ext_vector_type(4))) float f32x4;
typedef __attribute__((ext_vector_type(8))) short short8;

#define E_DIM 512
#define HW    4096      // 64*64 spatial per batch
#define NT    32768     // total tokens

// round-to-nearest-even f32 -> bf16 bits
__device__ __forceinline__ short f2bf(float f) {
  union { float f; unsigned u; } v; v.f = f;
  unsigned u = v.u;
  u += 0x7fffu + ((u >> 16) & 1u);
  return (short)(u >> 16);
}

// swizzled element index into a [rows][64] bf16 LDS tile (row stride 128B).
// byte ^= ((row&7)<<4)  -> conflict-free-ish ds_read_b128 (G4 / T2)
__device__ __forceinline__ int swzidx(int row, int k) {
  return row * 64 + (k ^ ((row & 7) << 3));
}

// ---------------------------------------------------------------------------
// Kernel 1: fused window-partition + input projection (q/k/v via blockIdx.z)
// C[tok, e] = sum_f X[b][f][hw] * W[e][f] + bias[e]
// output layout: O[(n*64 + t) * 512 + e]  (window-token order, bf16)
// ---------------------------------------------------------------------------
__global__ __launch_bounds__(256) void proj_kernel(
    const float* __restrict__ Xq, const float* __restrict__ Xk,
    const float* __restrict__ Xv,
    const float* __restrict__ Wfull, const float* __restrict__ Bfull,
    short* __restrict__ Oq, short* __restrict__ Ok, short* __restrict__ Ov)
{
  const int z = blockIdx.z;
  const float* X    = (z == 0) ? Xq : (z == 1) ? Xk : Xv;
  const float* Wp   = Wfull + (size_t)z * E_DIM * E_DIM;
  const float* bias = Bfull + z * E_DIM;
  short* O          = (z == 0) ? Oq : (z == 1) ? Ok : Ov;

  const int tok0 = blockIdx.x * 128;       // 128 natural tokens (one batch)
  const int e0   = blockIdx.y * 128;
  const int b    = tok0 >> 12;
  const int hw0  = tok0 & (HW - 1);
  const float* Xb = X + (size_t)b * E_DIM * HW;

  __shared__ short lA[128 * 64];   // X tile  [m(tok)][k(f)] swizzled
  __shared__ short lB[128 * 64];   // W tile  [n(e)][k(f)]   swizzled

  const int tid  = threadIdx.x;
  const int lane = tid & 63, wv = tid >> 6;
  const int wm = wv >> 1, wn = wv & 1;
  const int lr = lane & 15, lg = lane >> 4;

  f32x4 acc[4][4];
#pragma unroll
  for (int i = 0; i < 4; ++i)
#pragma unroll
    for (int j = 0; j < 4; ++j) acc[i][j] = (f32x4){0.f, 0.f, 0.f, 0.f};

  const int am4 = (tid & 31) * 4;   // A-stage: m group
  const int ak8 = (tid >> 5) * 8;   // A-stage: k group
  const int brow = tid >> 1;        // B-stage: e row
  const int bkh  = (tid & 1) * 32;  // B-stage: k half

  for (int k0 = 0; k0 < E_DIM; k0 += 64) {
    if (k0) __syncthreads();
    // --- stage A: coalesced float4 along tokens, transpose to [m][k] bf16
    f32x4 av[8];
#pragma unroll
    for (int j = 0; j < 8; ++j)
      av[j] = *(const f32x4*)&Xb[(size_t)(k0 + ak8 + j) * HW + hw0 + am4];
#pragma unroll
    for (int mi = 0; mi < 4; ++mi) {
      short8 s;
#pragma unroll
      for (int j = 0; j < 8; ++j) s[j] = f2bf(av[j][mi]);
      *(short8*)&lA[swzidx(am4 + mi, ak8)] = s;
    }
    // --- stage B: W rows are k-contiguous already
    const float* wr = Wp + (size_t)(e0 + brow) * E_DIM + k0 + bkh;
    f32x4 wv4[8];
#pragma unroll
    for (int j = 0; j < 8; ++j) wv4[j] = *(const f32x4*)&wr[j * 4];
#pragma unroll
    for (int c = 0; c < 4; ++c) {
      short8 s;
#pragma unroll
      for (int j = 0; j < 8; ++j) s[j] = f2bf(wv4[c * 2 + (j >> 2)][j & 3]);
      *(short8*)&lB[swzidx(brow, bkh + c * 8)] = s;
    }
    __syncthreads();
    // --- compute: 2 k-steps of 16x16x32, 4x4 fragments per wave
#pragma unroll
    for (int ks = 0; ks < 2; ++ks) {
      const int kk = ks * 32 + lg * 8;
      short8 af[4], bf[4];
#pragma unroll
      for (int i = 0; i < 4; ++i)
        af[i] = *(const short8*)&lA[swzidx(wm * 64 + i * 16 + lr, kk)];
#pragma unroll
      for (int j = 0; j < 4; ++j)
        bf[j] = *(const short8*)&lB[swzidx(wn * 64 + j * 16 + lr, kk)];
#pragma unroll
      for (int i = 0; i < 4; ++i)
#pragma unroll
        for (int j = 0; j < 4; ++j)
          acc[i][j] = __builtin_amdgcn_mfma_f32_16x16x32_bf16(af[i], bf[j], acc[i][j], 0, 0, 0);
    }
  }

  // --- epilogue: bias + bf16, scatter into window-token layout
  float bj[4];
#pragma unroll
  for (int j = 0; j < 4; ++j) bj[j] = bias[e0 + wn * 64 + j * 16 + lr];
#pragma unroll
  for (int i = 0; i < 4; ++i) {
#pragma unroll
    for (int r = 0; r < 4; ++r) {
      const int token = tok0 + wm * 64 + i * 16 + lg * 4 + r;
      const int hw = token & (HW - 1);
      const int h = hw >> 6, w = hw & 63;
      const int nwin = ((token >> 12) << 6) + ((h >> 3) << 3) + (w >> 3);
      const int twin = ((h & 7) << 3) + (w & 7);
      short* orow = O + ((size_t)(nwin * 64 + twin) << 9) + e0 + wn * 64 + lr;
#pragma unroll
      for (int j = 0; j < 4; ++j)
        orow[j * 16] = f2bf(acc[i][j][r] + bj[j]);
    }
  }
}

// ---------------------------------------------------------------------------
// Kernel 2: windowed attention, one block (4 waves) per (window, head)
// ---------------------------------------------------------------------------
__global__ __launch_bounds__(256) void attn_kernel(
    const short* __restrict__ Qp, const short* __restrict__ Kp,
    const short* __restrict__ Vp, short* __restrict__ Ob)
{
  const int nwin = blockIdx.x, head = blockIdx.y;
  const int base = nwin * (64 * E_DIM) + head * 64;

  __shared__ short lQ[64 * 64];   // Q [t][d]  (later reused for P [tq][tk])
  __shared__ short lK[64 * 64];   // K [t][d]
  __shared__ short lVT[64 * 64];  // V^T [d][t]

  const int tid = threadIdx.x;
  {
    const int row = tid >> 2, sg = (tid & 3) * 16;
    const int go = base + row * E_DIM + sg;
    *(short8*)&lQ[swzidx(row, sg)]     = *(const short8*)&Qp[go];
    *(short8*)&lQ[swzidx(row, sg + 8)] = *(const short8*)&Qp[go + 8];
    *(short8*)&lK[swzidx(row, sg)]     = *(const short8*)&Kp[go];
    *(short8*)&lK[swzidx(row, sg + 8)] = *(const short8*)&Kp[go + 8];
    const int tv = tid & 63, d0 = (tid >> 6) * 16;
    const int gv = base + tv * E_DIM + d0;
    short8 v0 = *(const short8*)&Vp[gv];
    short8 v1 = *(const short8*)&Vp[gv + 8];
#pragma unroll
    for (int ii = 0; ii < 8; ++ii) lVT[swzidx(d0 + ii, tv)] = v0[ii];
#pragma unroll
    for (int ii = 0; ii < 8; ++ii) lVT[swzidx(d0 + 8 + ii, tv)] = v1[ii];
  }
  __syncthreads();

  const int lane = tid & 63, wv = tid >> 6;
  const int lr = lane & 15, lg = lane >> 4;
  const int m0 = wv * 16;   // this wave's 16 query rows

  // S = Q K^T  (rows m0..m0+15, all 64 cols)
  f32x4 s[4];
#pragma unroll
  for (int j = 0; j < 4; ++j) s[j] = (f32x4){0.f, 0.f, 0.f, 0.f};
#pragma unroll
  for (int ks = 0; ks < 2; ++ks) {
    const int kk = ks * 32 + lg * 8;
    short8 a = *(const short8*)&lQ[swzidx(m0 + lr, kk)];
#pragma unroll
    for (int j = 0; j < 4; ++j) {
      short8 b = *(const short8*)&lK[swzidx(j * 16 + lr, kk)];
      s[j] = __builtin_amdgcn_mfma_f32_16x16x32_bf16(a, b, s[j], 0, 0, 0);
    }
  }

  // row softmax (scale 1/sqrt(64)=0.125 folded into exp2)
  const float cexp = 0.125f * 1.4426950408889634f;
  float p[4][4], rs[4];
#pragma unroll
  for (int r = 0; r < 4; ++r) {
    float mx = fmaxf(fmaxf(s[0][r], s[1][r]), fmaxf(s[2][r], s[3][r]));
    mx = fmaxf(mx, __shfl_xor(mx, 1));
    mx = fmaxf(mx, __shfl_xor(mx, 2));
    mx = fmaxf(mx, __shfl_xor(mx, 4));
    mx = fmaxf(mx, __shfl_xor(mx, 8));
    float sm = 0.f;
#pragma unroll
    for (int j = 0; j < 4; ++j) { p[j][r] = exp2f((s[j][r] - mx) * cexp); sm += p[j][r]; }
    sm += __shfl_xor(sm, 1); sm += __shfl_xor(sm, 2);
    sm += __shfl_xor(sm, 4); sm += __shfl_xor(sm, 8);
    rs[r] = 1.0f / sm;   // fold normalization into epilogue
  }

  // P -> LDS (reuse lQ rows m0..m0+15; wave-private rows, no barrier needed)
#pragma unroll
  for (int r = 0; r < 4; ++r)
#pragma unroll
    for (int j = 0; j < 4; ++j)
      lQ[swzidx(m0 + lg * 4 + r, j * 16 + lr)] = f2bf(p[j][r]);

  // O = P V
  f32x4 o[4];
#pragma unroll
  for (int nf = 0; nf < 4; ++nf) o[nf] = (f32x4){0.f, 0.f, 0.f, 0.f};
#pragma unroll
  for (int ks = 0; ks < 2; ++ks) {
    const int kk = ks * 32 + lg * 8;
    short8 a = *(const short8*)&lQ[swzidx(m0 + lr, kk)];
#pragma unroll
    for (int nf = 0; nf < 4; ++nf) {
      short8 b = *(const short8*)&lVT[swzidx(nf * 16 + lr, kk)];
      o[nf] = __builtin_amdgcn_mfma_f32_16x16x32_bf16(a, b, o[nf], 0, 0, 0);
    }
  }

#pragma unroll
  for (int r = 0; r < 4; ++r) {
    const int t = m0 + lg * 4 + r;
    short* orow = Ob + base + t * E_DIM + lr;
#pragma unroll
    for (int nf = 0; nf < 4; ++nf)
      orow[nf * 16] = f2bf(o[nf][r] * rs[r]);
  }
}

// ---------------------------------------------------------------------------
// Kernel 3: output projection + window-unpartition.
// Computes C^T:  C[e, tok] = sum_f Wo[e][f] * o[tok][f] + bo[e]
// so both operands are k-contiguous and the f32 store is w-contiguous.
// ---------------------------------------------------------------------------
__global__ __launch_bounds__(256) void oproj_kernel(
    const short* __restrict__ Ob, const float* __restrict__ Wo,
    const float* __restrict__ bo, float* __restrict__ Out)
{
  const int tok0 = blockIdx.x * 128;   // window-ordered tokens
  const int e0   = blockIdx.y * 128;

  __shared__ short lA[128 * 64];   // Wo [e][k]
  __shared__ short lB[128 * 64];   // o  [tok][k]

  const int tid  = threadIdx.x;
  const int lane = tid & 63, wv = tid >> 6;
  const int wm = wv >> 1, wn = wv & 1;
  const int lr = lane & 15, lg = lane >> 4;

  f32x4 acc[4][4];
#pragma unroll
  for (int i = 0; i < 4; ++i)
#pragma unroll
    for (int j = 0; j < 4; ++j) acc[i][j] = (f32x4){0.f, 0.f, 0.f, 0.f};

  const int row = tid >> 1;
  const int kh  = (tid & 1) * 32;

  for (int k0 = 0; k0 < E_DIM; k0 += 64) {
    if (k0) __syncthreads();
    // stage Wo (f32 -> bf16)
    const float* wr = Wo + (size_t)(e0 + row) * E_DIM + k0 + kh;
    f32x4 wv4[8];
#pragma unroll
    for (int j = 0; j < 8; ++j) wv4[j] = *(const f32x4*)&wr[j * 4];
#pragma unroll
    for (int c = 0; c < 4; ++c) {
      short8 s;
#pragma unroll
      for (int j = 0; j < 8; ++j) s[j] = f2bf(wv4[c * 2 + (j >> 2)][j & 3]);
      *(short8*)&lA[swzidx(row, kh + c * 8)] = s;
    }
    // stage o (bf16 copy)
    const short* og = Ob + (size_t)(tok0 + row) * E_DIM + k0 + kh;
#pragma unroll
    for (int c = 0; c < 4; ++c)
      *(short8*)&lB[swzidx(row, kh + c * 8)] = *(const short8*)&og[c * 8];
    __syncthreads();
#pragma unroll
    for (int ks = 0; ks < 2; ++ks) {
      const int kk = ks * 32 + lg * 8;
      short8 af[4], bf[4];
#pragma unroll
      for (int i = 0; i < 4; ++i)
        af[i] = *(const short8*)&lA[swzidx(wm * 64 + i * 16 + lr, kk)];
#pragma unroll
      for (int j = 0; j < 4; ++j)
        bf[j] = *(const short8*)&lB[swzidx(wn * 64 + j * 16 + lr, kk)];
#pragma unroll
      for (int i = 0; i < 4; ++i)
#pragma unroll
        for (int j = 0; j < 4; ++j)
          acc[i][j] = __builtin_amdgcn_mfma_f32_16x16x32_bf16(af[i], bf[j], acc[i][j], 0, 0, 0);
    }
  }

  // epilogue: rows = e, cols = window-token -> unpartition to (B,E,H,W) f32
#pragma unroll
  for (int i = 0; i < 4; ++i) {
#pragma unroll
    for (int r = 0; r < 4; ++r) {
      const int e = e0 + wm * 64 + i * 16 + lg * 4 + r;
      const float be = bo[e];
#pragma unroll
      for (int j = 0; j < 4; ++j) {
        const int wtok = tok0 + wn * 64 + j * 16 + lr;
        const int n = wtok >> 6, t = wtok & 63;
        const int b = n >> 6;
        const int h = (((n >> 3) & 7) << 3) + (t >> 3);
        const int w = ((n & 7) << 3) + (t & 7);
        Out[(size_t)b * (E_DIM * HW) + (size_t)e * HW + (h << 6) + w] =
            acc[i][j][r] + be;
      }
    }
  }
}

// ---------------------------------------------------------------------------
extern "C" void kernel_launch(void* const* d_in, const int* in_sizes, int n_in,
                              void* d_out, int out_size, void* d_ws, size_t ws_size,
                              hipStream_t stream) {
  const float* q     = (const float*)d_in[0];
  const float* k     = (const float*)d_in[1];
  const float* v     = (const float*)d_in[2];
  const float* in_w  = (const float*)d_in[3];   // (1536, 512)
  const float* in_b  = (const float*)d_in[4];   // (1536,)
  const float* out_w = (const float*)d_in[5];   // (512, 512)
  const float* out_b = (const float*)d_in[6];   // (512,)
  float* out = (float*)d_out;

  // workspace: 4 bf16 tensors of (32768, 512) = 32 MB each (128 MB total)
  short* qp = (short*)d_ws;
  short* kp = qp + (size_t)NT * E_DIM;
  short* vp = kp + (size_t)NT * E_DIM;
  short* ob = vp + (size_t)NT * E_DIM;

  proj_kernel<<<dim3(NT / 128, E_DIM / 128, 3), 256, 0, stream>>>(
      q, k, v, in_w, in_b, qp, kp, vp);
  attn_kernel<<<dim3(512, 8), 256, 0, stream>>>(qp, kp, vp, ob);
  oproj_kernel<<<dim3(NT / 128, E_DIM / 128), 256, 0, stream>>>(
      ob, out_w, out_b, out);
}

// Round 2
// 218.979 us; speedup vs baseline: 1.1956x; 1.1956x over previous
//
#include <hip/hip_runtime.h>

typedef __attribute__((ext_vector_type(4))) float f32x4;
typedef __attribute__((ext_vector_type(8))) short short8;

#define E_DIM 512
#define HW    4096      // 64*64 spatial per batch
#define NT    32768     // total tokens
#define NTE   16777216  // NT*E_DIM elements (32 MiB as bf16)

// bf16 copies of in_proj_w (rows 0..1535) and out_proj_w (rows 1536..2047)
__device__ short g_wbf[2048 * E_DIM];

// round-to-nearest-even f32 -> bf16 bits
__device__ __forceinline__ short f2bf(float f) {
  union { float f; unsigned u; } v; v.f = f;
  unsigned u = v.u;
  u += 0x7fffu + ((u >> 16) & 1u);
  return (short)(u >> 16);
}
__device__ __forceinline__ unsigned pack_bf2(float lo, float hi) {
  return (unsigned)(unsigned short)f2bf(lo) | ((unsigned)(unsigned short)f2bf(hi) << 16);
}

// swizzled element index into a [rows][64] bf16 LDS tile (row stride 128B).
// 16B-chunk position p within row holds source chunk p ^ (row&7)   (T2)
__device__ __forceinline__ int swzidx(int row, int k) {
  return row * 64 + (k ^ ((row & 7) << 3));
}

// async global->LDS, 16B per lane; LDS dest = uniform base + lane*16
#define GLOAD16(g, l) __builtin_amdgcn_global_load_lds( \
    (const __attribute__((address_space(1))) void*)(g), \
    (__attribute__((address_space(3))) void*)(l), 16, 0, 0)

// ---------------------------------------------------------------------------
// convert_w: f32 -> bf16 for both weight matrices into g_wbf
// ---------------------------------------------------------------------------
__global__ __launch_bounds__(256) void convert_w(
    const float* __restrict__ w_in, const float* __restrict__ w_out)
{
  const size_t off = ((size_t)blockIdx.x * 256 + threadIdx.x) * 8;
  const float* src = (off < 786432) ? (w_in + off) : (w_out + (off - 786432));
  f32x4 a = *(const f32x4*)src, b = *(const f32x4*)(src + 4);
  short8 s;
#pragma unroll
  for (int j = 0; j < 4; ++j) { s[j] = f2bf(a[j]); s[4 + j] = f2bf(b[j]); }
  *(short8*)&g_wbf[off] = s;
}

// ---------------------------------------------------------------------------
// convert_x: (B,E,H,W) f32 -> bf16 [window-token][f] layout (partition fused)
// block = (b,h) row x 128-f chunk; LDS transpose [128 f][66 w]
// ---------------------------------------------------------------------------
__global__ __launch_bounds__(256) void convert_x(
    const float* __restrict__ q, const float* __restrict__ k,
    const float* __restrict__ v,
    short* __restrict__ xq, short* __restrict__ xk, short* __restrict__ xv)
{
  const int z  = blockIdx.z;
  const int fc = blockIdx.y;                 // 128-f chunk
  const int bh = blockIdx.x;                 // b*64 + h
  const int b = bh >> 6, h = bh & 63;
  const float* X = ((z == 0) ? q : (z == 1) ? k : v)
                 + (size_t)b * (E_DIM * HW) + (size_t)(fc * 128) * HW + h * 64;
  short* O = (z == 0) ? xq : (z == 1) ? xk : xv;
  const int tb = b * HW + (h >> 3) * 512 + (h & 7) * 8;  // token base for (b,h)

  __shared__ short lds[128 * 66];
  const int t = threadIdx.x;
#pragma unroll
  for (int rep = 0; rep < 2; ++rep) {
    const int fl = rep * 64 + (t >> 2);
    const int w0 = (t & 3) * 16;
    const float* src = X + (size_t)fl * HW + w0;
    f32x4 a0 = *(const f32x4*)(src);
    f32x4 a1 = *(const f32x4*)(src + 4);
    f32x4 a2 = *(const f32x4*)(src + 8);
    f32x4 a3 = *(const f32x4*)(src + 12);
    unsigned* dst = (unsigned*)&lds[fl * 66 + w0];
    dst[0] = pack_bf2(a0[0], a0[1]); dst[1] = pack_bf2(a0[2], a0[3]);
    dst[2] = pack_bf2(a1[0], a1[1]); dst[3] = pack_bf2(a1[2], a1[3]);
    dst[4] = pack_bf2(a2[0], a2[1]); dst[5] = pack_bf2(a2[2], a2[3]);
    dst[6] = pack_bf2(a3[0], a3[1]); dst[7] = pack_bf2(a3[2], a3[3]);
  }
  __syncthreads();
  const int w = t >> 2, fs = (t & 3) * 8;
  const int tok = tb + (w >> 3) * 64 + (w & 7);
  short* orow = O + (size_t)tok * E_DIM + fc * 128;
#pragma unroll
  for (int i = 0; i < 4; ++i) {
    short8 s;
#pragma unroll
    for (int j = 0; j < 8; ++j) s[j] = lds[(fs + 32 * i + j) * 66 + w];
    *(short8*)&orow[fs + 32 * i] = s;
  }
}

// ---------------------------------------------------------------------------
// proj: pure bf16 GEMM, m97 structure (global_load_lds staging, 128x128 tile)
// C[tok, e] = X[tok,:] . W[e,:] + bias[e]   (tokens already window-ordered)
// ---------------------------------------------------------------------------
__global__ __launch_bounds__(256) void proj_kernel(
    const short* __restrict__ xq, const short* __restrict__ xk,
    const short* __restrict__ xv, const float* __restrict__ Bfull,
    short* __restrict__ Oq, short* __restrict__ Ok, short* __restrict__ Ov)
{
  // XCD-chunked swizzle (T1), y-fastest so 4 e-blocks sharing X-tile co-reside
  const int wg  = blockIdx.x;                 // 3072 = 3 * 256 * 4
  const int swz = (wg & 7) * 384 + (wg >> 3);
  const int z = swz >> 10, rr = swz & 1023;
  const int tok0 = (rr >> 2) * 128, e0 = (rr & 3) * 128;

  const short* X  = (z == 0) ? xq : (z == 1) ? xk : xv;
  const short* Wz = g_wbf + z * (E_DIM * E_DIM);
  const float* bias = Bfull + z * E_DIM;
  short* O = (z == 0) ? Oq : (z == 1) ? Ok : Ov;

  __shared__ short lA[128 * 64];
  __shared__ short lB[128 * 64];

  const int tid = threadIdx.x, lane = tid & 63, wv = tid >> 6;
  const int wm = wv >> 1, wn = wv & 1;
  const int lr = lane & 15, lg = lane >> 4;
  // per-lane pre-swizzled source (rule #21: inverse-swz source + swz read)
  const int lrow = lane >> 3;                  // row within 8-row group
  const int lcoff = (((lane & 7) ^ lrow) * 8); // source k-chunk offset (elems)

  f32x4 acc[4][4];
#pragma unroll
  for (int i = 0; i < 4; ++i)
#pragma unroll
    for (int j = 0; j < 4; ++j) acc[i][j] = (f32x4){0.f, 0.f, 0.f, 0.f};

  for (int k0 = 0; k0 < E_DIM; k0 += 64) {
    if (k0) __syncthreads();
#pragma unroll
    for (int qq = 0; qq < 4; ++qq) {
      const int rowb = wv * 32 + qq * 8;
      GLOAD16(X  + (size_t)(tok0 + rowb + lrow) * E_DIM + k0 + lcoff, &lA[rowb * 64]);
      GLOAD16(Wz + (size_t)(e0   + rowb + lrow) * E_DIM + k0 + lcoff, &lB[rowb * 64]);
    }
    __syncthreads();
#pragma unroll
    for (int ks = 0; ks < 2; ++ks) {
      const int kk = ks * 32 + lg * 8;
      short8 af[4], bf[4];
#pragma unroll
      for (int i = 0; i < 4; ++i)
        af[i] = *(const short8*)&lA[swzidx(wm * 64 + i * 16 + lr, kk)];
#pragma unroll
      for (int j = 0; j < 4; ++j)
        bf[j] = *(const short8*)&lB[swzidx(wn * 64 + j * 16 + lr, kk)];
#pragma unroll
      for (int i = 0; i < 4; ++i)
#pragma unroll
        for (int j = 0; j < 4; ++j)
          acc[i][j] = __builtin_amdgcn_mfma_f32_16x16x32_bf16(af[i], bf[j], acc[i][j], 0, 0, 0);
    }
  }

  float bj[4];
#pragma unroll
  for (int j = 0; j < 4; ++j) bj[j] = bias[e0 + wn * 64 + j * 16 + lr];
#pragma unroll
  for (int i = 0; i < 4; ++i) {
#pragma unroll
    for (int r = 0; r < 4; ++r) {
      const int token = tok0 + wm * 64 + i * 16 + lg * 4 + r;
      short* orow = O + ((size_t)token << 9) + e0 + wn * 64 + lr;
#pragma unroll
      for (int j = 0; j < 4; ++j)
        orow[j * 16] = f2bf(acc[i][j][r] + bj[j]);
    }
  }
}

// ---------------------------------------------------------------------------
// attn: one block (4 waves) per (head, window)  [head-fastest for L2 reuse]
// ---------------------------------------------------------------------------
__global__ __launch_bounds__(256) void attn_kernel(
    const short* __restrict__ Qp, const short* __restrict__ Kp,
    const short* __restrict__ Vp, short* __restrict__ Ob)
{
  const int head = blockIdx.x, nwin = blockIdx.y;
  const int base = nwin * (64 * E_DIM) + head * 64;

  __shared__ short lQ[64 * 64];   // Q [t][d]  (later reused for P)
  __shared__ short lK[64 * 64];
  __shared__ short lVT[64 * 64];  // V^T [d][t]

  const int tid = threadIdx.x;
  {
    const int row = tid >> 2, sg = (tid & 3) * 16;
    const int go = base + row * E_DIM + sg;
    *(short8*)&lQ[swzidx(row, sg)]     = *(const short8*)&Qp[go];
    *(short8*)&lQ[swzidx(row, sg + 8)] = *(const short8*)&Qp[go + 8];
    *(short8*)&lK[swzidx(row, sg)]     = *(const short8*)&Kp[go];
    *(short8*)&lK[swzidx(row, sg + 8)] = *(const short8*)&Kp[go + 8];
    const int tv = tid & 63, d0 = (tid >> 6) * 16;
    const int gv = base + tv * E_DIM + d0;
    short8 v0 = *(const short8*)&Vp[gv];
    short8 v1 = *(const short8*)&Vp[gv + 8];
#pragma unroll
    for (int ii = 0; ii < 8; ++ii) lVT[swzidx(d0 + ii, tv)] = v0[ii];
#pragma unroll
    for (int ii = 0; ii < 8; ++ii) lVT[swzidx(d0 + 8 + ii, tv)] = v1[ii];
  }
  __syncthreads();

  const int lane = tid & 63, wv = tid >> 6;
  const int lr = lane & 15, lg = lane >> 4;
  const int m0 = wv * 16;

  f32x4 s[4];
#pragma unroll
  for (int j = 0; j < 4; ++j) s[j] = (f32x4){0.f, 0.f, 0.f, 0.f};
#pragma unroll
  for (int ks = 0; ks < 2; ++ks) {
    const int kk = ks * 32 + lg * 8;
    short8 a = *(const short8*)&lQ[swzidx(m0 + lr, kk)];
#pragma unroll
    for (int j = 0; j < 4; ++j) {
      short8 b = *(const short8*)&lK[swzidx(j * 16 + lr, kk)];
      s[j] = __builtin_amdgcn_mfma_f32_16x16x32_bf16(a, b, s[j], 0, 0, 0);
    }
  }

  const float cexp = 0.125f * 1.4426950408889634f;
  float p[4][4], rs[4];
#pragma unroll
  for (int r = 0; r < 4; ++r) {
    float mx = fmaxf(fmaxf(s[0][r], s[1][r]), fmaxf(s[2][r], s[3][r]));
    mx = fmaxf(mx, __shfl_xor(mx, 1));
    mx = fmaxf(mx, __shfl_xor(mx, 2));
    mx = fmaxf(mx, __shfl_xor(mx, 4));
    mx = fmaxf(mx, __shfl_xor(mx, 8));
    float sm = 0.f;
#pragma unroll
    for (int j = 0; j < 4; ++j) { p[j][r] = exp2f((s[j][r] - mx) * cexp); sm += p[j][r]; }
    sm += __shfl_xor(sm, 1); sm += __shfl_xor(sm, 2);
    sm += __shfl_xor(sm, 4); sm += __shfl_xor(sm, 8);
    rs[r] = 1.0f / sm;
  }

#pragma unroll
  for (int r = 0; r < 4; ++r)
#pragma unroll
    for (int j = 0; j < 4; ++j)
      lQ[swzidx(m0 + lg * 4 + r, j * 16 + lr)] = f2bf(p[j][r]);

  f32x4 o[4];
#pragma unroll
  for (int nf = 0; nf < 4; ++nf) o[nf] = (f32x4){0.f, 0.f, 0.f, 0.f};
#pragma unroll
  for (int ks = 0; ks < 2; ++ks) {
    const int kk = ks * 32 + lg * 8;
    short8 a = *(const short8*)&lQ[swzidx(m0 + lr, kk)];
#pragma unroll
    for (int nf = 0; nf < 4; ++nf) {
      short8 b = *(const short8*)&lVT[swzidx(nf * 16 + lr, kk)];
      o[nf] = __builtin_amdgcn_mfma_f32_16x16x32_bf16(a, b, o[nf], 0, 0, 0);
    }
  }

#pragma unroll
  for (int r = 0; r < 4; ++r) {
    const int t = m0 + lg * 4 + r;
    short* orow = Ob + base + t * E_DIM + lr;
#pragma unroll
    for (int nf = 0; nf < 4; ++nf)
      orow[nf * 16] = f2bf(o[nf][r] * rs[r]);
  }
}

// ---------------------------------------------------------------------------
// oproj: C[e, tok] = Wo[e,:] . o[tok,:] + bo[e], unpartition in epilogue
// ---------------------------------------------------------------------------
__global__ __launch_bounds__(256) void oproj_kernel(
    const short* __restrict__ Ob, const float* __restrict__ bo,
    float* __restrict__ Out)
{
  const int wg  = blockIdx.x;                // 1024 = 256 * 4
  const int swz = (wg & 7) * 128 + (wg >> 3);
  const int tok0 = (swz >> 2) * 128, e0 = (swz & 3) * 128;
  const short* Wo = g_wbf + 1536 * E_DIM;

  __shared__ short lA[128 * 64];   // Wo [e][k]
  __shared__ short lB[128 * 64];   // o  [tok][k]

  const int tid = threadIdx.x, lane = tid & 63, wv = tid >> 6;
  const int wm = wv >> 1, wn = wv & 1;
  const int lr = lane & 15, lg = lane >> 4;
  const int lrow = lane >> 3;
  const int lcoff = (((lane & 7) ^ lrow) * 8);

  f32x4 acc[4][4];
#pragma unroll
  for (int i = 0; i < 4; ++i)
#pragma unroll
    for (int j = 0; j < 4; ++j) acc[i][j] = (f32x4){0.f, 0.f, 0.f, 0.f};

  for (int k0 = 0; k0 < E_DIM; k0 += 64) {
    if (k0) __syncthreads();
#pragma unroll
    for (int qq = 0; qq < 4; ++qq) {
      const int rowb = wv * 32 + qq * 8;
      GLOAD16(Wo + (size_t)(e0   + rowb + lrow) * E_DIM + k0 + lcoff, &lA[rowb * 64]);
      GLOAD16(Ob + (size_t)(tok0 + rowb + lrow) * E_DIM + k0 + lcoff, &lB[rowb * 64]);
    }
    __syncthreads();
#pragma unroll
    for (int ks = 0; ks < 2; ++ks) {
      const int kk = ks * 32 + lg * 8;
      short8 af[4], bf[4];
#pragma unroll
      for (int i = 0; i < 4; ++i)
        af[i] = *(const short8*)&lA[swzidx(wm * 64 + i * 16 + lr, kk)];
#pragma unroll
      for (int j = 0; j < 4; ++j)
        bf[j] = *(const short8*)&lB[swzidx(wn * 64 + j * 16 + lr, kk)];
#pragma unroll
      for (int i = 0; i < 4; ++i)
#pragma unroll
        for (int j = 0; j < 4; ++j)
          acc[i][j] = __builtin_amdgcn_mfma_f32_16x16x32_bf16(af[i], bf[j], acc[i][j], 0, 0, 0);
    }
  }

#pragma unroll
  for (int i = 0; i < 4; ++i) {
#pragma unroll
    for (int r = 0; r < 4; ++r) {
      const int e = e0 + wm * 64 + i * 16 + lg * 4 + r;
      const float be = bo[e];
#pragma unroll
      for (int j = 0; j < 4; ++j) {
        const int wtok = tok0 + wn * 64 + j * 16 + lr;
        const int n = wtok >> 6, t = wtok & 63;
        const int b = n >> 6;
        const int h = (((n >> 3) & 7) << 3) + (t >> 3);
        const int w = ((n & 7) << 3) + (t & 7);
        Out[(size_t)b * (E_DIM * HW) + (size_t)e * HW + (h << 6) + w] =
            acc[i][j][r] + be;
      }
    }
  }
}

// ---------------------------------------------------------------------------
extern "C" void kernel_launch(void* const* d_in, const int* in_sizes, int n_in,
                              void* d_out, int out_size, void* d_ws, size_t ws_size,
                              hipStream_t stream) {
  const float* q     = (const float*)d_in[0];
  const float* k     = (const float*)d_in[1];
  const float* v     = (const float*)d_in[2];
  const float* in_w  = (const float*)d_in[3];
  const float* in_b  = (const float*)d_in[4];
  const float* out_w = (const float*)d_in[5];
  const float* out_b = (const float*)d_in[6];
  float* out = (float*)d_out;

  // scratch plan (d_ws = 128 MiB committed, d_out doubles as early scratch):
  //   d_out: xq @0, xk @32MiB        (both dead before oproj writes d_out)
  //   d_ws : xv @0 (reused as ob after proj), qp @32Mi, kp @64Mi, vp @96Mi
  short* xq = (short*)d_out;
  short* xk = xq + NTE;
  short* xv = (short*)d_ws;
  short* qp = xv + NTE;
  short* kp = qp + NTE;
  short* vp = kp + NTE;
  short* ob = xv;

  convert_w<<<512, 256, 0, stream>>>(in_w, out_w);
  convert_x<<<dim3(512, 4, 3), 256, 0, stream>>>(q, k, v, xq, xk, xv);
  proj_kernel<<<3072, 256, 0, stream>>>(xq, xk, xv, in_b, qp, kp, vp);
  attn_kernel<<<dim3(8, 512), 256, 0, stream>>>(qp, kp, vp, ob);
  oproj_kernel<<<1024, 256, 0, stream>>>(ob, out_b, out);
}

// Round 3
// 196.343 us; speedup vs baseline: 1.3334x; 1.1153x over previous
//
#include <hip/hip_runtime.h>

typedef __attribute__((ext_vector_type(4))) float f32x4;
typedef __attribute__((ext_vector_type(8))) short short8;

#define E_DIM 512
#define HW    4096      // 64*64 spatial per batch
#define NT    32768     // total tokens
#define NTE   16777216  // NT*E_DIM elements (32 MiB as bf16)

// bf16 copies of in_proj_w (rows 0..1535) and out_proj_w (rows 1536..2047)
__device__ short g_wbf[2048 * E_DIM];

// round-to-nearest-even f32 -> bf16 bits
__device__ __forceinline__ short f2bf(float f) {
  union { float f; unsigned u; } v; v.f = f;
  unsigned u = v.u;
  u += 0x7fffu + ((u >> 16) & 1u);
  return (short)(u >> 16);
}
__device__ __forceinline__ unsigned pack_bf2(float lo, float hi) {
  return (unsigned)(unsigned short)f2bf(lo) | ((unsigned)(unsigned short)f2bf(hi) << 16);
}

// attn-kernel swizzle: [rows][64] bf16 tile, chunk ^= (row&7)
__device__ __forceinline__ int swzidx(int row, int k) {
  return row * 64 + (k ^ ((row & 7) << 3));
}

// ---- 256x32 bf16 GEMM staging tile: 128B lines = 2 rows x 4 chunks,
// physical chunk = logical ^ (line&7)  -> 2-way (free) ds_read_b128 banks
__device__ __forceinline__ void chunk_map(int c, int& row, int& kc) {
  const int line = c >> 3;
  const int l = (c & 7) ^ (line & 7);
  row = line * 2 + (l >> 2);
  kc = l & 3;
}
__device__ __forceinline__ int tile_off(int row, int kc) {  // in shorts
  const int line = row >> 1;
  const int phys = (((row & 1) << 2) | kc) ^ (line & 7);
  return line * 64 + phys * 8;
}

// async global->LDS, 16B per lane; LDS dest = wave-uniform base (+lane*16 HW)
#define GLOAD16(g, l) __builtin_amdgcn_global_load_lds( \
    (const __attribute__((address_space(1))) void*)(g), \
    (__attribute__((address_space(3))) void*)(l), 16, 0, 0)

#define WAITVM(N) asm volatile("s_waitcnt vmcnt(" #N ")" ::: "memory")
#define FULL_BAR() do { asm volatile("" ::: "memory"); \
  __builtin_amdgcn_s_barrier(); asm volatile("" ::: "memory"); } while (0)

// ---------------------------------------------------------------------------
// convert_w: f32 -> bf16 for both weight matrices into g_wbf
// ---------------------------------------------------------------------------
__global__ __launch_bounds__(256) void convert_w(
    const float* __restrict__ w_in, const float* __restrict__ w_out)
{
  const size_t off = ((size_t)blockIdx.x * 256 + threadIdx.x) * 8;
  const float* src = (off < 786432) ? (w_in + off) : (w_out + (off - 786432));
  f32x4 a = *(const f32x4*)src, b = *(const f32x4*)(src + 4);
  short8 s;
#pragma unroll
  for (int j = 0; j < 4; ++j) { s[j] = f2bf(a[j]); s[4 + j] = f2bf(b[j]); }
  *(short8*)&g_wbf[off] = s;
}

// ---------------------------------------------------------------------------
// convert_x: (B,E,H,W) f32 -> bf16 [window-token][f] layout (partition fused)
// ---------------------------------------------------------------------------
__global__ __launch_bounds__(256) void convert_x(
    const float* __restrict__ q, const float* __restrict__ k,
    const float* __restrict__ v,
    short* __restrict__ xq, short* __restrict__ xk, short* __restrict__ xv)
{
  const int z  = blockIdx.z;
  const int fc = blockIdx.y;
  const int bh = blockIdx.x;
  const int b = bh >> 6, h = bh & 63;
  const float* X = ((z == 0) ? q : (z == 1) ? k : v)
                 + (size_t)b * (E_DIM * HW) + (size_t)(fc * 128) * HW + h * 64;
  short* O = (z == 0) ? xq : (z == 1) ? xk : xv;
  const int tb = b * HW + (h >> 3) * 512 + (h & 7) * 8;

  __shared__ short lds[128 * 66];
  const int t = threadIdx.x;
#pragma unroll
  for (int rep = 0; rep < 2; ++rep) {
    const int fl = rep * 64 + (t >> 2);
    const int w0 = (t & 3) * 16;
    const float* src = X + (size_t)fl * HW + w0;
    f32x4 a0 = *(const f32x4*)(src);
    f32x4 a1 = *(const f32x4*)(src + 4);
    f32x4 a2 = *(const f32x4*)(src + 8);
    f32x4 a3 = *(const f32x4*)(src + 12);
    unsigned* dst = (unsigned*)&lds[fl * 66 + w0];
    dst[0] = pack_bf2(a0[0], a0[1]); dst[1] = pack_bf2(a0[2], a0[3]);
    dst[2] = pack_bf2(a1[0], a1[1]); dst[3] = pack_bf2(a1[2], a1[3]);
    dst[4] = pack_bf2(a2[0], a2[1]); dst[5] = pack_bf2(a2[2], a2[3]);
    dst[6] = pack_bf2(a3[0], a3[1]); dst[7] = pack_bf2(a3[2], a3[3]);
  }
  __syncthreads();
  const int w = t >> 2, fs = (t & 3) * 8;
  const int tok = tb + (w >> 3) * 64 + (w & 7);
  short* orow = O + (size_t)tok * E_DIM + fc * 128;
#pragma unroll
  for (int i = 0; i < 4; ++i) {
    short8 s;
#pragma unroll
    for (int j = 0; j < 8; ++j) s[j] = lds[(fs + 32 * i + j) * 66 + w];
    *(short8*)&orow[fs + 32 * i] = s;
  }
}

// ---------------------------------------------------------------------------
// proj: 256x256 tile, 8-wave, BK=32, 4-slot LDS ring, counted-vmcnt pipeline
// C[tok, e] = X[tok,:] . W[e,:] + bias[e]
// ---------------------------------------------------------------------------
__global__ __launch_bounds__(512, 2) void proj_kernel(
    const short* __restrict__ xq, const short* __restrict__ xk,
    const short* __restrict__ xv, const float* __restrict__ Bfull,
    short* __restrict__ Oq, short* __restrict__ Ok, short* __restrict__ Ov)
{
  // XCD-chunked bijective swizzle, 768 = 8 * 96
  const int wg  = blockIdx.x;
  const int swz = (wg & 7) * 96 + (wg >> 3);
  const int z = swz >> 8, rr = swz & 255;
  const int e0 = (rr & 1) << 8, tok0 = (rr >> 1) << 8;

  const short* X  = (z == 0) ? xq : (z == 1) ? xk : xv;
  const short* Wz = g_wbf + z * (E_DIM * E_DIM);
  const float* bias = Bfull + z * E_DIM;
  short* O = (z == 0) ? Oq : (z == 1) ? Ok : Ov;

  __shared__ short lds[4 * 16384];   // 4 ring slots x (A 256x32 + B 256x32)

  const int tid = threadIdx.x, lane = tid & 63, wv = tid >> 6;
  const int wm = wv >> 2, wn = wv & 3;
  const int lr = lane & 15, lg = lane >> 4;

  // staging source map (inverse of LDS swizzle; rule #21)
  int r0, k0c, r1, k1c;
  chunk_map(tid, r0, k0c);
  chunk_map(512 + tid, r1, k1c);
  const short* sA0 = X  + (size_t)(tok0 + r0) * E_DIM + k0c * 8;
  const short* sA1 = X  + (size_t)(tok0 + r1) * E_DIM + k1c * 8;
  const short* sB0 = Wz + (size_t)(e0 + r0) * E_DIM + k0c * 8;
  const short* sB1 = Wz + (size_t)(e0 + r1) * E_DIM + k1c * 8;
  const int dc0 = (wv * 64) * 8, dc1 = (512 + wv * 64) * 8;  // wave-uniform

  // ds_read fragment offsets (within slot)
  int aoff[8], boff[4];
#pragma unroll
  for (int i = 0; i < 8; ++i) aoff[i] = tile_off(wm * 128 + i * 16 + lr, lg);
#pragma unroll
  for (int j = 0; j < 4; ++j) boff[j] = 8192 + tile_off(wn * 64 + j * 16 + lr, lg);

  f32x4 acc[8][4];
#pragma unroll
  for (int i = 0; i < 8; ++i)
#pragma unroll
    for (int j = 0; j < 4; ++j) acc[i][j] = (f32x4){0.f, 0.f, 0.f, 0.f};

  auto STAGE = [&](int slot, int kt) {
    const int sb = slot * 16384, ko = kt * 32;
    GLOAD16(sA0 + ko, &lds[sb + dc0]);
    GLOAD16(sA1 + ko, &lds[sb + dc1]);
    GLOAD16(sB0 + ko, &lds[sb + 8192 + dc0]);
    GLOAD16(sB1 + ko, &lds[sb + 8192 + dc1]);
  };
  auto COMPUTE = [&](int slot) {
    const int sb = slot * 16384;
    short8 af[8], bf[4];
#pragma unroll
    for (int i = 0; i < 8; ++i) af[i] = *(const short8*)&lds[sb + aoff[i]];
#pragma unroll
    for (int j = 0; j < 4; ++j) bf[j] = *(const short8*)&lds[sb + boff[j]];
    __builtin_amdgcn_s_setprio(1);
#pragma unroll
    for (int i = 0; i < 8; ++i)
#pragma unroll
      for (int j = 0; j < 4; ++j)
        acc[i][j] = __builtin_amdgcn_mfma_f32_16x16x32_bf16(af[i], bf[j], acc[i][j], 0, 0, 0);
    __builtin_amdgcn_s_setprio(0);
  };

  STAGE(0, 0); STAGE(1, 1); STAGE(2, 2);
  for (int t = 0; t < 13; ++t) {
    WAITVM(8);             // tile t landed; tiles t+1,t+2 still in flight
    FULL_BAR();
    STAGE((t + 3) & 3, t + 3);   // slot of t-1: reads done before this barrier
    COMPUTE(t & 3);
  }
  WAITVM(8); FULL_BAR(); COMPUTE(13 & 3);
  WAITVM(4); FULL_BAR(); COMPUTE(14 & 3);
  WAITVM(0); FULL_BAR(); COMPUTE(15 & 3);

  float bj[4];
#pragma unroll
  for (int j = 0; j < 4; ++j) bj[j] = bias[e0 + wn * 64 + j * 16 + lr];
#pragma unroll
  for (int i = 0; i < 8; ++i) {
#pragma unroll
    for (int r = 0; r < 4; ++r) {
      const int token = tok0 + wm * 128 + i * 16 + lg * 4 + r;
      short* orow = O + ((size_t)token << 9) + e0 + wn * 64 + lr;
#pragma unroll
      for (int j = 0; j < 4; ++j)
        orow[j * 16] = f2bf(acc[i][j][r] + bj[j]);
    }
  }
}

// ---------------------------------------------------------------------------
// attn: one block (4 waves) per (head, window)
// ---------------------------------------------------------------------------
__global__ __launch_bounds__(256) void attn_kernel(
    const short* __restrict__ Qp, const short* __restrict__ Kp,
    const short* __restrict__ Vp, short* __restrict__ Ob)
{
  const int head = blockIdx.x, nwin = blockIdx.y;
  const int base = nwin * (64 * E_DIM) + head * 64;

  __shared__ short lQ[64 * 64];
  __shared__ short lK[64 * 64];
  __shared__ short lVT[64 * 64];

  const int tid = threadIdx.x;
  {
    const int row = tid >> 2, sg = (tid & 3) * 16;
    const int go = base + row * E_DIM + sg;
    *(short8*)&lQ[swzidx(row, sg)]     = *(const short8*)&Qp[go];
    *(short8*)&lQ[swzidx(row, sg + 8)] = *(const short8*)&Qp[go + 8];
    *(short8*)&lK[swzidx(row, sg)]     = *(const short8*)&Kp[go];
    *(short8*)&lK[swzidx(row, sg + 8)] = *(const short8*)&Kp[go + 8];
    const int tv = tid & 63, d0 = (tid >> 6) * 16;
    const int gv = base + tv * E_DIM + d0;
    short8 v0 = *(const short8*)&Vp[gv];
    short8 v1 = *(const short8*)&Vp[gv + 8];
#pragma unroll
    for (int ii = 0; ii < 8; ++ii) lVT[swzidx(d0 + ii, tv)] = v0[ii];
#pragma unroll
    for (int ii = 0; ii < 8; ++ii) lVT[swzidx(d0 + 8 + ii, tv)] = v1[ii];
  }
  __syncthreads();

  const int lane = tid & 63, wv = tid >> 6;
  const int lr = lane & 15, lg = lane >> 4;
  const int m0 = wv * 16;

  f32x4 s[4];
#pragma unroll
  for (int j = 0; j < 4; ++j) s[j] = (f32x4){0.f, 0.f, 0.f, 0.f};
#pragma unroll
  for (int ks = 0; ks < 2; ++ks) {
    const int kk = ks * 32 + lg * 8;
    short8 a = *(const short8*)&lQ[swzidx(m0 + lr, kk)];
#pragma unroll
    for (int j = 0; j < 4; ++j) {
      short8 b = *(const short8*)&lK[swzidx(j * 16 + lr, kk)];
      s[j] = __builtin_amdgcn_mfma_f32_16x16x32_bf16(a, b, s[j], 0, 0, 0);
    }
  }

  const float cexp = 0.125f * 1.4426950408889634f;
  float p[4][4], rs[4];
#pragma unroll
  for (int r = 0; r < 4; ++r) {
    float mx = fmaxf(fmaxf(s[0][r], s[1][r]), fmaxf(s[2][r], s[3][r]));
    mx = fmaxf(mx, __shfl_xor(mx, 1));
    mx = fmaxf(mx, __shfl_xor(mx, 2));
    mx = fmaxf(mx, __shfl_xor(mx, 4));
    mx = fmaxf(mx, __shfl_xor(mx, 8));
    float sm = 0.f;
#pragma unroll
    for (int j = 0; j < 4; ++j) { p[j][r] = exp2f((s[j][r] - mx) * cexp); sm += p[j][r]; }
    sm += __shfl_xor(sm, 1); sm += __shfl_xor(sm, 2);
    sm += __shfl_xor(sm, 4); sm += __shfl_xor(sm, 8);
    rs[r] = 1.0f / sm;
  }

#pragma unroll
  for (int r = 0; r < 4; ++r)
#pragma unroll
    for (int j = 0; j < 4; ++j)
      lQ[swzidx(m0 + lg * 4 + r, j * 16 + lr)] = f2bf(p[j][r]);

  f32x4 o[4];
#pragma unroll
  for (int nf = 0; nf < 4; ++nf) o[nf] = (f32x4){0.f, 0.f, 0.f, 0.f};
#pragma unroll
  for (int ks = 0; ks < 2; ++ks) {
    const int kk = ks * 32 + lg * 8;
    short8 a = *(const short8*)&lQ[swzidx(m0 + lr, kk)];
#pragma unroll
    for (int nf = 0; nf < 4; ++nf) {
      short8 b = *(const short8*)&lVT[swzidx(nf * 16 + lr, kk)];
      o[nf] = __builtin_amdgcn_mfma_f32_16x16x32_bf16(a, b, o[nf], 0, 0, 0);
    }
  }

#pragma unroll
  for (int r = 0; r < 4; ++r) {
    const int t = m0 + lg * 4 + r;
    short* orow = Ob + base + t * E_DIM + lr;
#pragma unroll
    for (int nf = 0; nf < 4; ++nf)
      orow[nf * 16] = f2bf(o[nf][r] * rs[r]);
  }
}

// ---------------------------------------------------------------------------
// oproj: C[e, tok] = Wo[e,:] . o[tok,:] + bo[e]; same ring pipeline
// ---------------------------------------------------------------------------
__global__ __launch_bounds__(512, 2) void oproj_kernel(
    const short* __restrict__ Ob, const float* __restrict__ bo,
    float* __restrict__ Out)
{
  const int wg  = blockIdx.x;                 // 256 = 8 * 32
  const int swz = (wg & 7) * 32 + (wg >> 3);
  const int e0 = (swz & 1) << 8, tok0 = (swz >> 1) << 8;
  const short* Wo = g_wbf + 1536 * E_DIM;

  __shared__ short lds[4 * 16384];

  const int tid = threadIdx.x, lane = tid & 63, wv = tid >> 6;
  const int wm = wv >> 2, wn = wv & 3;
  const int lr = lane & 15, lg = lane >> 4;

  int r0, k0c, r1, k1c;
  chunk_map(tid, r0, k0c);
  chunk_map(512 + tid, r1, k1c);
  const short* sA0 = Wo + (size_t)(e0 + r0) * E_DIM + k0c * 8;
  const short* sA1 = Wo + (size_t)(e0 + r1) * E_DIM + k1c * 8;
  const short* sB0 = Ob + (size_t)(tok0 + r0) * E_DIM + k0c * 8;
  const short* sB1 = Ob + (size_t)(tok0 + r1) * E_DIM + k1c * 8;
  const int dc0 = (wv * 64) * 8, dc1 = (512 + wv * 64) * 8;

  int aoff[8], boff[4];
#pragma unroll
  for (int i = 0; i < 8; ++i) aoff[i] = tile_off(wm * 128 + i * 16 + lr, lg);
#pragma unroll
  for (int j = 0; j < 4; ++j) boff[j] = 8192 + tile_off(wn * 64 + j * 16 + lr, lg);

  f32x4 acc[8][4];
#pragma unroll
  for (int i = 0; i < 8; ++i)
#pragma unroll
    for (int j = 0; j < 4; ++j) acc[i][j] = (f32x4){0.f, 0.f, 0.f, 0.f};

  auto STAGE = [&](int slot, int kt) {
    const int sb = slot * 16384, ko = kt * 32;
    GLOAD16(sA0 + ko, &lds[sb + dc0]);
    GLOAD16(sA1 + ko, &lds[sb + dc1]);
    GLOAD16(sB0 + ko, &lds[sb + 8192 + dc0]);
    GLOAD16(sB1 + ko, &lds[sb + 8192 + dc1]);
  };
  auto COMPUTE = [&](int slot) {
    const int sb = slot * 16384;
    short8 af[8], bf[4];
#pragma unroll
    for (int i = 0; i < 8; ++i) af[i] = *(const short8*)&lds[sb + aoff[i]];
#pragma unroll
    for (int j = 0; j < 4; ++j) bf[j] = *(const short8*)&lds[sb + boff[j]];
    __builtin_amdgcn_s_setprio(1);
#pragma unroll
    for (int i = 0; i < 8; ++i)
#pragma unroll
      for (int j = 0; j < 4; ++j)
        acc[i][j] = __builtin_amdgcn_mfma_f32_16x16x32_bf16(af[i], bf[j], acc[i][j], 0, 0, 0);
    __builtin_amdgcn_s_setprio(0);
  };

  STAGE(0, 0); STAGE(1, 1); STAGE(2, 2);
  for (int t = 0; t < 13; ++t) {
    WAITVM(8);
    FULL_BAR();
    STAGE((t + 3) & 3, t + 3);
    COMPUTE(t & 3);
  }
  WAITVM(8); FULL_BAR(); COMPUTE(13 & 3);
  WAITVM(4); FULL_BAR(); COMPUTE(14 & 3);
  WAITVM(0); FULL_BAR(); COMPUTE(15 & 3);

#pragma unroll
  for (int i = 0; i < 8; ++i) {
#pragma unroll
    for (int r = 0; r < 4; ++r) {
      const int e = e0 + wm * 128 + i * 16 + lg * 4 + r;
      const float be = bo[e];
#pragma unroll
      for (int j = 0; j < 4; ++j) {
        const int wtok = tok0 + wn * 64 + j * 16 + lr;
        const int n = wtok >> 6, t = wtok & 63;
        const int b = n >> 6;
        const int h = (((n >> 3) & 7) << 3) + (t >> 3);
        const int w = ((n & 7) << 3) + (t & 7);
        Out[(size_t)b * (E_DIM * HW) + (size_t)e * HW + (h << 6) + w] =
            acc[i][j][r] + be;
      }
    }
  }
}

// ---------------------------------------------------------------------------
extern "C" void kernel_launch(void* const* d_in, const int* in_sizes, int n_in,
                              void* d_out, int out_size, void* d_ws, size_t ws_size,
                              hipStream_t stream) {
  const float* q     = (const float*)d_in[0];
  const float* k     = (const float*)d_in[1];
  const float* v     = (const float*)d_in[2];
  const float* in_w  = (const float*)d_in[3];
  const float* in_b  = (const float*)d_in[4];
  const float* out_w = (const float*)d_in[5];
  const float* out_b = (const float*)d_in[6];
  float* out = (float*)d_out;

  // scratch plan: d_out holds xq,xk early (dead before oproj writes);
  // d_ws: xv @0 (reused as ob), qp @32Mi, kp @64Mi, vp @96Mi
  short* xq = (short*)d_out;
  short* xk = xq + NTE;
  short* xv = (short*)d_ws;
  short* qp = xv + NTE;
  short* kp = qp + NTE;
  short* vp = kp + NTE;
  short* ob = xv;

  convert_w<<<512, 256, 0, stream>>>(in_w, out_w);
  convert_x<<<dim3(512, 4, 3), 256, 0, stream>>>(q, k, v, xq, xk, xv);
  proj_kernel<<<768, 512, 0, stream>>>(xq, xk, xv, in_b, qp, kp, vp);
  attn_kernel<<<dim3(8, 512), 256, 0, stream>>>(qp, kp, vp, ob);
  oproj_kernel<<<256, 512, 0, stream>>>(ob, out_b, out);
}